// Round 8
// baseline (668.028 us; speedup 1.0000x reference)
//
#include <hip/hip_runtime.h>
#include <math.h>

#define N_NODES 100000
#define N_EDGES 3200000
#define EPS_F 1e-6f

#define NSLICE  8
#define SLICE_N 12500                     // 8 * 12500 = 100000
#define NCHUNK  32
#define CHUNK_E (N_EDGES / NCHUNK)        // 100000 exactly

// repack batching
#define RJ      8
#define R_EPB   (256 * RJ)                // 2048 edges per block

// ws layout (float indices) — 64 + 4E + 33N = 16,100,064 floats = 61.4 MiB
// (identical footprint to the R7 layout that the harness already granted)
//   [1..4]   : sum(p0), sum(p1), sum(p0^2), sum(p1^2)
//   [5]      : sum(node_sum^2)
//   SD_OFF   : packed int2 (src,dst)[N_EDGES]     (25.6 MB)
//   VS_OFF   : vsrc[N_EDGES]  (v at src, edge-order)
//   VD_OFF   : vdst[N_EDGES]
//   PART_OFF : partials[NCHUNK][N_NODES]          (12.8 MB)
//   V_OFF    : packed v[N_NODES]                  (0.4 MB)
#define SD_OFF    64
#define VS_OFF    (SD_OFF + 2 * N_EDGES)
#define VD_OFF    (VS_OFF + N_EDGES)
#define PART_OFF  (VD_OFF + N_EDGES)
#define V_OFF     (PART_OFF + NCHUNK * N_NODES)
#define WS_FLOATS (V_OFF + N_NODES)

__device__ __forceinline__ float wave_reduce(float v) {
    #pragma unroll
    for (int off = 32; off > 0; off >>= 1) v += __shfl_down(v, off, 64);
    return v;
}

__device__ __forceinline__ void fadd_agent(float* p, float v) {
    unsafeAtomicAdd(p, v);   // only scalar-acc updates
}

// ---------------- pass 0: pack v = nf[:,0] into a dense 400 KB table ----------------
__global__ __launch_bounds__(256) void packv_kernel(
    const float* __restrict__ nf, float* __restrict__ ws)
{
    const int i = blockIdx.x * blockDim.x + threadIdx.x;
    if (i < N_NODES) ws[V_OFF + i] = nf[i * 4];
}

// ---------------- pass 1: repack edge_index -> int2 sd[]; variance sums ----------------
__global__ __launch_bounds__(256) void repack_kernel(
    const void*   __restrict__ eidx,
    const float2* __restrict__ params,
    float*        __restrict__ ws)
{
    const int*       i32 = (const int*)eidx;
    const long long* i64 = (const long long*)eidx;

    // int64 values < 2^31 have zero hi-words at every odd int32 slot;
    // int32 has random node ids there (16 zeros ~ impossible).
    int any = 0;
    #pragma unroll
    for (int k = 1; k < 32; k += 2) any |= i32[k];
    const bool is32 = (any != 0);

    int2*  sd  = (int2*)(ws + SD_OFF);
    float* acc = ws + 1;

    const int e_base = blockIdx.x * R_EPB + threadIdx.x;

    int srcv[RJ], dstv[RJ];
    float2 epv[RJ];

    #pragma unroll
    for (int j = 0; j < RJ; ++j) {
        int e = e_base + j * 256;
        e = (e < N_EDGES) ? e : (N_EDGES - 1);
        if (is32) { srcv[j] = i32[e]; dstv[j] = i32[N_EDGES + e]; }
        else      { srcv[j] = (int)i64[e]; dstv[j] = (int)i64[N_EDGES + e]; }
        epv[j] = params[e];
    }

    float s0 = 0.f, s1 = 0.f, q0 = 0.f, q1 = 0.f;
    #pragma unroll
    for (int j = 0; j < RJ; ++j) {
        const int e = e_base + j * 256;
        if (e < N_EDGES) {
            sd[e] = make_int2(srcv[j], dstv[j]);
            const float2 ep = epv[j];
            s0 += ep.x; s1 += ep.y;
            q0 += ep.x * ep.x; q1 += ep.y * ep.y;
        }
    }

    s0 = wave_reduce(s0); s1 = wave_reduce(s1);
    q0 = wave_reduce(q0); q1 = wave_reduce(q1);
    if ((threadIdx.x & 63) == 0) {
        fadd_agent(acc + 0, s0); fadd_agent(acc + 1, s1);
        fadd_agent(acc + 2, q0); fadd_agent(acc + 3, q1);
    }
}

// ---------------- pass 2: LDS-sliced gather: vsrc[e], vdst[e] ----------------
// Block (slice s, chunk c): the slice's v-values sit in LDS; random access is
// a ds_read (~12 cyc/wave-instr) instead of a global L2 miss (MSHR-limited).
// blockIdx = s*NCHUNK + c -> all blocks of chunk c share blockIdx%8 (one XCD),
// so sd[] re-reads and vsrc/vdst partial-line writes stay in that XCD's L2.
__global__ __launch_bounds__(512) void vgather_kernel(float* __restrict__ ws)
{
    __shared__ float vs_lds[SLICE_N];   // 50 KB

    const int c  = blockIdx.x & (NCHUNK - 1);
    const int s  = blockIdx.x >> 5;
    const int lo = s * SLICE_N;

    const float* vtab = ws + V_OFF;
    for (int j = threadIdx.x; j < SLICE_N; j += 512) vs_lds[j] = vtab[lo + j];
    __syncthreads();

    const int2* sd   = (const int2*)(ws + SD_OFF);
    float*      vsrc = ws + VS_OFF;
    float*      vdst = ws + VD_OFF;

    const int e0 = c * CHUNK_E;
    const int e1 = e0 + CHUNK_E;

    for (int base = e0 + threadIdx.x; base < e1; base += 2048) {
        int2 sd4[4];
        #pragma unroll
        for (int k = 0; k < 4; ++k) {
            int e = base + k * 512;
            e = (e < e1) ? e : (e1 - 1);   // clamp: loads stay unconditional
            sd4[k] = sd[e];
        }
        #pragma unroll
        for (int k = 0; k < 4; ++k) {
            const int e = base + k * 512;
            if (e < e1) {
                const unsigned us = (unsigned)(sd4[k].x - lo);
                const unsigned ud = (unsigned)(sd4[k].y - lo);
                if (us < SLICE_N) vsrc[e] = vs_lds[us];
                if (ud < SLICE_N) vdst[e] = vs_lds[ud];
            }
        }
    }
}

// ---------------- pass 3: LDS-binned scatter; cur computed inline ----------------
__global__ __launch_bounds__(512) void scatter_kernel(
    const float*  __restrict__ logits,
    const float2* __restrict__ params,
    float*        __restrict__ ws)
{
    __shared__ float bins[SLICE_N];   // 50 KB

    const int c  = blockIdx.x & (NCHUNK - 1);
    const int s  = blockIdx.x >> 5;
    const int lo = s * SLICE_N;

    for (int j = threadIdx.x; j < SLICE_N; j += 512) bins[j] = 0.f;
    __syncthreads();

    const int2*  sd   = (const int2*)(ws + SD_OFF);
    const float* vsrc = ws + VS_OFF;
    const float* vdst = ws + VD_OFF;

    const int e0 = c * CHUNK_E;
    const int e1 = e0 + CHUNK_E;

    for (int base = e0 + threadIdx.x; base < e1; base += 2048) {
        int2 sd4[4];
        #pragma unroll
        for (int k = 0; k < 4; ++k) {
            int e = base + k * 512;
            e = (e < e1) ? e : (e1 - 1);   // clamp: loads stay unconditional
            sd4[k] = sd[e];
        }
        #pragma unroll
        for (int k = 0; k < 4; ++k) {
            const int e = base + k * 512;
            if (e < e1) {
                const unsigned us = (unsigned)(sd4[k].x - lo);
                const unsigned ud = (unsigned)(sd4[k].y - lo);
                const bool bs = (us < SLICE_N);
                const bool bd = (ud < SLICE_N);
                if (bs || bd) {
                    const float  vdiff = fabsf(vsrc[e] - vdst[e]);
                    const float2 ep    = params[e];
                    const float  p     = 1.0f / (1.0f + __expf(-logits[e]));
                    const float  cur   = vdiff / (ep.x + ep.y + EPS_F) * p;
                    if (bd) atomicAdd(&bins[ud],  cur);
                    if (bs) atomicAdd(&bins[us], -cur);
                }
            }
        }
    }
    __syncthreads();

    float* p = ws + PART_OFF + (size_t)c * N_NODES + lo;
    for (int j = threadIdx.x; j < SLICE_N; j += 512) p[j] = bins[j];
}

// ---------------- pass 4: merge partials, sum of squares ----------------
__global__ __launch_bounds__(256) void kcl_kernel(float* __restrict__ ws)
{
    const int i = blockIdx.x * blockDim.x + threadIdx.x;
    float acc = 0.f;
    if (i < N_NODES) {
        const float* p = ws + PART_OFF + i;
        float s = 0.f;
        #pragma unroll 8
        for (int c = 0; c < NCHUNK; ++c) s += p[(size_t)c * N_NODES];
        acc = s * s;
    }
    acc = wave_reduce(acc);
    if ((threadIdx.x & 63) == 0) fadd_agent(ws + 5, acc);
}

__global__ void final_kernel(const float* __restrict__ ws, float* __restrict__ out)
{
    const float s0 = ws[1], s1 = ws[2], q0 = ws[3], q1 = ws[4], k = ws[5];
    const float n  = (float)N_EDGES;
    const float var0 = (q0 - s0 * s0 / n) / (n - 1.0f);
    const float var1 = (q1 - s1 * s1 / n) / (n - 1.0f);
    out[0] = k / (float)N_NODES + 0.5f * (var0 + var1);
}

// ---------------- fallback (ws too small): agent-atomic scatter ----------------
#define FB_NODE_OFF 64
__global__ __launch_bounds__(256) void edge_kernel_fb(
    const float*  __restrict__ nf,
    const void*   __restrict__ eidx,
    const float*  __restrict__ logits,
    const float2* __restrict__ params,
    float*        __restrict__ ws)
{
    const int*       i32 = (const int*)eidx;
    const long long* i64 = (const long long*)eidx;
    int any = 0;
    #pragma unroll
    for (int k = 1; k < 32; k += 2) any |= i32[k];
    const bool is32 = (any != 0);

    float* node_sum = ws + FB_NODE_OFF;
    float* acc      = ws + 1;

    float s0 = 0.f, s1 = 0.f, q0 = 0.f, q1 = 0.f;
    const int tid    = blockIdx.x * blockDim.x + threadIdx.x;
    const int stride = gridDim.x * blockDim.x;
    for (int i = tid; i < N_EDGES; i += stride) {
        int src, dst;
        if (is32) { src = i32[i]; dst = i32[N_EDGES + i]; }
        else      { src = (int)i64[i]; dst = (int)i64[N_EDGES + i]; }
        const float2 ep = params[i];
        const float  p  = 1.0f / (1.0f + __expf(-logits[i]));
        const float cur = fabsf(nf[src * 4] - nf[dst * 4]) / (ep.x + ep.y + EPS_F) * p;
        fadd_agent(node_sum + dst,  cur);
        fadd_agent(node_sum + src, -cur);
        s0 += ep.x; s1 += ep.y; q0 += ep.x * ep.x; q1 += ep.y * ep.y;
    }
    s0 = wave_reduce(s0); s1 = wave_reduce(s1);
    q0 = wave_reduce(q0); q1 = wave_reduce(q1);
    if ((threadIdx.x & 63) == 0) {
        fadd_agent(acc + 0, s0); fadd_agent(acc + 1, s1);
        fadd_agent(acc + 2, q0); fadd_agent(acc + 3, q1);
    }
}

__global__ __launch_bounds__(256) void kcl_kernel_fb(float* __restrict__ ws)
{
    const float* node_sum = ws + FB_NODE_OFF;
    float acc = 0.f;
    const int tid    = blockIdx.x * blockDim.x + threadIdx.x;
    const int stride = gridDim.x * blockDim.x;
    for (int i = tid; i < N_NODES; i += stride) {
        const float v = node_sum[i];
        acc += v * v;
    }
    acc = wave_reduce(acc);
    if ((threadIdx.x & 63) == 0) fadd_agent(ws + 5, acc);
}

extern "C" void kernel_launch(void* const* d_in, const int* in_sizes, int n_in,
                              void* d_out, int out_size, void* d_ws, size_t ws_size,
                              hipStream_t stream) {
    const float*  nf     = (const float*)d_in[0];
    const void*   eidx   = d_in[1];
    const float*  logits = (const float*)d_in[2];
    const float2* params = (const float2*)d_in[3];
    float* ws  = (float*)d_ws;
    float* out = (float*)d_out;

    const size_t need = (size_t)WS_FLOATS * sizeof(float);   // 61.4 MiB (same as R7)

    if (ws_size >= need) {
        hipMemsetAsync(d_ws, 0, 256, stream);
        packv_kernel<<<(N_NODES + 255) / 256, 256, 0, stream>>>(nf, ws);
        repack_kernel<<<(N_EDGES + R_EPB - 1) / R_EPB, 256, 0, stream>>>(eidx, params, ws);
        vgather_kernel<<<NCHUNK * NSLICE, 512, 0, stream>>>(ws);
        scatter_kernel<<<NCHUNK * NSLICE, 512, 0, stream>>>(logits, params, ws);
        kcl_kernel<<<(N_NODES + 255) / 256, 256, 0, stream>>>(ws);
    } else {
        hipMemsetAsync(d_ws, 0, 256 + (size_t)N_NODES * sizeof(float), stream);
        edge_kernel_fb<<<2048, 256, 0, stream>>>(nf, eidx, logits, params, ws);
        kcl_kernel_fb<<<200, 256, 0, stream>>>(ws);
    }

    final_kernel<<<1, 1, 0, stream>>>(ws, out);
}

// Round 9
// 336.191 us; speedup vs baseline: 1.9871x; 1.9871x over previous
//
#include <hip/hip_runtime.h>
#include <math.h>

#define N_NODES 100000
#define N_EDGES 3200000
#define EPS_F 1e-6f

#define NSLICE  8
#define SLICE_N 12500                     // 8 * 12500 = 100000, 50 KB LDS

// vgather: 100 chunks x 8 slices = 800 blocks (≈3/CU via LDS)
#define VCHUNK   100
#define V_PAIRS  (N_EDGES / 2 / VCHUNK)   // 16000 edge-pairs per chunk
// scatter: 32 chunks x 8 slices = 256 blocks (1/CU, 16 waves @1024 thr)
#define SCHUNK   32
#define S_PAIRS  (N_EDGES / 2 / SCHUNK)   // 25000 edge-pairs per chunk

// ws layout (float indices) — 64 + 2E + 2E + SCHUNK*N + N = 16,100,064 floats
// = 61.4 MiB (identical to the R7/R8 footprint the harness already granted)
//   [1..4]   : sum(p0), sum(p1), sum(p0^2), sum(p1^2)
//   [5]      : sum(node_sum^2)
//   SD_OFF   : packed int2 (src,dst)[N_EDGES]     (25.6 MB)
//   VV_OFF   : float2 (v[src], v[dst])[N_EDGES]   (25.6 MB)
//   PART_OFF : partials[SCHUNK][N_NODES]          (12.8 MB)
//   V_OFF    : packed v[N_NODES]                  (0.4 MB)
#define SD_OFF    64
#define VV_OFF    (SD_OFF + 2 * N_EDGES)
#define PART_OFF  (VV_OFF + 2 * N_EDGES)
#define V_OFF     (PART_OFF + SCHUNK * N_NODES)
#define WS_FLOATS (V_OFF + N_NODES)

__device__ __forceinline__ float wave_reduce(float v) {
    #pragma unroll
    for (int off = 32; off > 0; off >>= 1) v += __shfl_down(v, off, 64);
    return v;
}

__device__ __forceinline__ void fadd_agent(float* p, float v) {
    unsafeAtomicAdd(p, v);
}

// ---------------- pass 0: pack v = nf[:,0] into a dense 400 KB table ----------------
__global__ __launch_bounds__(256) void packv_kernel(
    const float* __restrict__ nf, float* __restrict__ ws)
{
    const int i = blockIdx.x * blockDim.x + threadIdx.x;
    if (i < N_NODES) ws[V_OFF + i] = nf[i * 4];
}

// ---------------- pass 1: dtype-normalize edge_index -> int2 sd[] ----------------
// Pure vectorized transform: 2 edges per thread, int4 in / int4 out, no arrays,
// no reductions — nothing for the register allocator to serialize.
__global__ __launch_bounds__(256) void repack_kernel(
    const void* __restrict__ eidx, float* __restrict__ ws)
{
    const int* i32 = (const int*)eidx;

    // int64 values < 2^31 have zero hi-words at every odd int32 slot;
    // int32 has random node ids there (16 zeros ~ impossible).
    int any = 0;
    #pragma unroll
    for (int k = 1; k < 32; k += 2) any |= i32[k];
    const bool is32 = (any != 0);

    const int t = blockIdx.x * blockDim.x + threadIdx.x;   // pair index
    if (t >= N_EDGES / 2) return;

    int4 out;
    if (is32) {
        const int2 a = ((const int2*)i32)[t];                    // src[2t], src[2t+1]
        const int2 b = ((const int2*)(i32 + N_EDGES))[t];        // dst[2t], dst[2t+1]
        out = make_int4(a.x, b.x, a.y, b.y);
    } else {
        const int4 a = ((const int4*)i32)[t];                    // src pair as 2x int64
        const int4 b = ((const int4*)(i32 + 2 * N_EDGES))[t];    // dst pair
        out = make_int4(a.x, b.x, a.z, b.z);
    }
    ((int4*)(ws + SD_OFF))[t] = out;
}

// ---------------- pass 2: variance partial sums over params ----------------
__global__ __launch_bounds__(256) void varsum_kernel(
    const float2* __restrict__ params, float* __restrict__ ws)
{
    __shared__ float red[4][4];
    const float4* p4 = (const float4*)params;   // 2 edges per float4
    const int n4 = N_EDGES / 2;

    float s0 = 0.f, s1 = 0.f, q0 = 0.f, q1 = 0.f;
    for (int t = blockIdx.x * blockDim.x + threadIdx.x; t < n4;
         t += gridDim.x * blockDim.x) {
        const float4 pp = p4[t];
        s0 += pp.x + pp.z; s1 += pp.y + pp.w;
        q0 += pp.x * pp.x + pp.z * pp.z;
        q1 += pp.y * pp.y + pp.w * pp.w;
    }
    s0 = wave_reduce(s0); s1 = wave_reduce(s1);
    q0 = wave_reduce(q0); q1 = wave_reduce(q1);

    const int wid = threadIdx.x >> 6;
    if ((threadIdx.x & 63) == 0) {
        red[wid][0] = s0; red[wid][1] = s1; red[wid][2] = q0; red[wid][3] = q1;
    }
    __syncthreads();
    if (threadIdx.x == 0) {
        float a0 = 0.f, a1 = 0.f, a2 = 0.f, a3 = 0.f;
        #pragma unroll
        for (int w = 0; w < 4; ++w) {
            a0 += red[w][0]; a1 += red[w][1]; a2 += red[w][2]; a3 += red[w][3];
        }
        fadd_agent(ws + 1, a0); fadd_agent(ws + 2, a1);
        fadd_agent(ws + 3, a2); fadd_agent(ws + 4, a3);
    }
}

// ---------------- pass 3: LDS-sliced gather -> vv[e] = (v[src], v[dst]) ----------------
// Duplicate processing of a clamped pair is benign (idempotent same-value store).
__global__ __launch_bounds__(1024) void vgather_kernel(float* __restrict__ ws)
{
    __shared__ float vs_lds[SLICE_N];   // 50 KB

    const int c  = blockIdx.x >> 3;            // chunk [0,100)
    const int s  = blockIdx.x & (NSLICE - 1);  // slice
    const int lo = s * SLICE_N;

    const float* vtab = ws + V_OFF;
    for (int j = threadIdx.x; j < SLICE_N; j += 1024) vs_lds[j] = vtab[lo + j];
    __syncthreads();

    const int4* sdp = (const int4*)(ws + SD_OFF);
    float*      vvx = ws + VV_OFF;             // vv[e].x at 2e, .y at 2e+1

    const int p0 = c * V_PAIRS;
    const int p1 = p0 + V_PAIRS;

    for (int p = p0 + threadIdx.x; p < p1; p += 1024) {
        const int4 q = sdp[p];                 // (s0,d0,s1,d1)
        const unsigned a = (unsigned)(q.x - lo);
        const unsigned b = (unsigned)(q.y - lo);
        const unsigned e = (unsigned)(q.z - lo);
        const unsigned f = (unsigned)(q.w - lo);
        if (a < SLICE_N) vvx[4 * (size_t)p + 0] = vs_lds[a];
        if (b < SLICE_N) vvx[4 * (size_t)p + 1] = vs_lds[b];
        if (e < SLICE_N) vvx[4 * (size_t)p + 2] = vs_lds[e];
        if (f < SLICE_N) vvx[4 * (size_t)p + 3] = vs_lds[f];
    }
}

// ---------------- pass 4: LDS-binned scatter; cur computed inline ----------------
__global__ __launch_bounds__(1024) void scatter_kernel(
    const float*  __restrict__ logits,
    const float2* __restrict__ params,
    float*        __restrict__ ws)
{
    __shared__ float bins[SLICE_N];   // 50 KB

    const int c  = blockIdx.x & (SCHUNK - 1);
    const int s  = blockIdx.x >> 5;
    const int lo = s * SLICE_N;

    for (int j = threadIdx.x; j < SLICE_N; j += 1024) bins[j] = 0.f;
    __syncthreads();

    const int4*   sdp = (const int4*)(ws + SD_OFF);
    const float2* vv  = (const float2*)(ws + VV_OFF);

    const int p0 = c * S_PAIRS;
    const int p1 = p0 + S_PAIRS;

    for (int p = p0 + threadIdx.x; p < p1; p += 1024) {
        const int4 q = sdp[p];
        // edge e0 = 2p
        {
            const unsigned ss = (unsigned)(q.x - lo);
            const unsigned ds = (unsigned)(q.y - lo);
            if (ss < SLICE_N || ds < SLICE_N) {
                const int e = 2 * p;
                const float2 v  = vv[e];
                const float2 ep = params[e];
                const float  pb = 1.0f / (1.0f + __expf(-logits[e]));
                const float cur = fabsf(v.x - v.y) / (ep.x + ep.y + EPS_F) * pb;
                if (ds < SLICE_N) atomicAdd(&bins[ds],  cur);
                if (ss < SLICE_N) atomicAdd(&bins[ss], -cur);
            }
        }
        // edge e1 = 2p+1
        {
            const unsigned ss = (unsigned)(q.z - lo);
            const unsigned ds = (unsigned)(q.w - lo);
            if (ss < SLICE_N || ds < SLICE_N) {
                const int e = 2 * p + 1;
                const float2 v  = vv[e];
                const float2 ep = params[e];
                const float  pb = 1.0f / (1.0f + __expf(-logits[e]));
                const float cur = fabsf(v.x - v.y) / (ep.x + ep.y + EPS_F) * pb;
                if (ds < SLICE_N) atomicAdd(&bins[ds],  cur);
                if (ss < SLICE_N) atomicAdd(&bins[ss], -cur);
            }
        }
    }
    __syncthreads();

    float* p = ws + PART_OFF + (size_t)c * N_NODES + lo;
    for (int j = threadIdx.x; j < SLICE_N; j += 1024) p[j] = bins[j];
}

// ---------------- pass 5: merge partials, sum of squares ----------------
__global__ __launch_bounds__(256) void kcl_kernel(float* __restrict__ ws)
{
    const int i = blockIdx.x * blockDim.x + threadIdx.x;
    float acc = 0.f;
    if (i < N_NODES) {
        const float* p = ws + PART_OFF + i;
        float s = 0.f;
        #pragma unroll 8
        for (int c = 0; c < SCHUNK; ++c) s += p[(size_t)c * N_NODES];
        acc = s * s;
    }
    acc = wave_reduce(acc);
    if ((threadIdx.x & 63) == 0) fadd_agent(ws + 5, acc);
}

__global__ void final_kernel(const float* __restrict__ ws, float* __restrict__ out)
{
    const float s0 = ws[1], s1 = ws[2], q0 = ws[3], q1 = ws[4], k = ws[5];
    const float n  = (float)N_EDGES;
    const float var0 = (q0 - s0 * s0 / n) / (n - 1.0f);
    const float var1 = (q1 - s1 * s1 / n) / (n - 1.0f);
    out[0] = k / (float)N_NODES + 0.5f * (var0 + var1);
}

// ---------------- fallback (ws too small): agent-atomic scatter ----------------
#define FB_NODE_OFF 64
__global__ __launch_bounds__(256) void edge_kernel_fb(
    const float*  __restrict__ nf,
    const void*   __restrict__ eidx,
    const float*  __restrict__ logits,
    const float2* __restrict__ params,
    float*        __restrict__ ws)
{
    const int*       i32 = (const int*)eidx;
    const long long* i64 = (const long long*)eidx;
    int any = 0;
    #pragma unroll
    for (int k = 1; k < 32; k += 2) any |= i32[k];
    const bool is32 = (any != 0);

    float* node_sum = ws + FB_NODE_OFF;
    float* acc      = ws + 1;

    float s0 = 0.f, s1 = 0.f, q0 = 0.f, q1 = 0.f;
    const int tid    = blockIdx.x * blockDim.x + threadIdx.x;
    const int stride = gridDim.x * blockDim.x;
    for (int i = tid; i < N_EDGES; i += stride) {
        int src, dst;
        if (is32) { src = i32[i]; dst = i32[N_EDGES + i]; }
        else      { src = (int)i64[i]; dst = (int)i64[N_EDGES + i]; }
        const float2 ep = params[i];
        const float  p  = 1.0f / (1.0f + __expf(-logits[i]));
        const float cur = fabsf(nf[src * 4] - nf[dst * 4]) / (ep.x + ep.y + EPS_F) * p;
        fadd_agent(node_sum + dst,  cur);
        fadd_agent(node_sum + src, -cur);
        s0 += ep.x; s1 += ep.y; q0 += ep.x * ep.x; q1 += ep.y * ep.y;
    }
    s0 = wave_reduce(s0); s1 = wave_reduce(s1);
    q0 = wave_reduce(q0); q1 = wave_reduce(q1);
    if ((threadIdx.x & 63) == 0) {
        fadd_agent(acc + 0, s0); fadd_agent(acc + 1, s1);
        fadd_agent(acc + 2, q0); fadd_agent(acc + 3, q1);
    }
}

__global__ __launch_bounds__(256) void kcl_kernel_fb(float* __restrict__ ws)
{
    const float* node_sum = ws + FB_NODE_OFF;
    float acc = 0.f;
    const int tid    = blockIdx.x * blockDim.x + threadIdx.x;
    const int stride = gridDim.x * blockDim.x;
    for (int i = tid; i < N_NODES; i += stride) {
        const float v = node_sum[i];
        acc += v * v;
    }
    acc = wave_reduce(acc);
    if ((threadIdx.x & 63) == 0) fadd_agent(ws + 5, acc);
}

extern "C" void kernel_launch(void* const* d_in, const int* in_sizes, int n_in,
                              void* d_out, int out_size, void* d_ws, size_t ws_size,
                              hipStream_t stream) {
    const float*  nf     = (const float*)d_in[0];
    const void*   eidx   = d_in[1];
    const float*  logits = (const float*)d_in[2];
    const float2* params = (const float2*)d_in[3];
    float* ws  = (float*)d_ws;
    float* out = (float*)d_out;

    const size_t need = (size_t)WS_FLOATS * sizeof(float);   // 61.4 MiB (same as R7/R8)

    if (ws_size >= need) {
        hipMemsetAsync(d_ws, 0, 256, stream);
        packv_kernel<<<(N_NODES + 255) / 256, 256, 0, stream>>>(nf, ws);
        repack_kernel<<<(N_EDGES / 2 + 255) / 256, 256, 0, stream>>>(eidx, ws);
        varsum_kernel<<<1024, 256, 0, stream>>>(params, ws);
        vgather_kernel<<<VCHUNK * NSLICE, 1024, 0, stream>>>(ws);
        scatter_kernel<<<SCHUNK * NSLICE, 1024, 0, stream>>>(logits, params, ws);
        kcl_kernel<<<(N_NODES + 255) / 256, 256, 0, stream>>>(ws);
    } else {
        hipMemsetAsync(d_ws, 0, 256 + (size_t)N_NODES * sizeof(float), stream);
        edge_kernel_fb<<<2048, 256, 0, stream>>>(nf, eidx, logits, params, ws);
        kcl_kernel_fb<<<200, 256, 0, stream>>>(ws);
    }

    final_kernel<<<1, 1, 0, stream>>>(ws, out);
}

// Round 10
// 326.805 us; speedup vs baseline: 2.0441x; 1.0287x over previous
//
#include <hip/hip_runtime.h>
#include <math.h>

#define N_NODES 100000
#define N_EDGES 3200000
#define EPS_F 1e-6f

#define NSLICE  8
#define SLICE_N 12500                     // 8 * 12500 = 100000, 50 KB LDS
#define NCHUNK  32
#define C_PAIRS (N_EDGES / 2 / NCHUNK)    // 50000 pairs (100K edges) per chunk

// ws layout (float indices) — 64 + 2E + E/1 + E + NCHUNK*N + N = 16,100,064
// floats = 61.4 MiB (identical footprint to R7/R8/R9 — already granted)
//   [1..4]   : sum(p0), sum(p1), sum(p0^2), sum(p1^2)
//   [5]      : sum(node_sum^2)
//   SD_OFF   : packed int2 (src,dst)[N_EDGES]     (25.6 MB)
//   VD_OFF   : v_src[e] then in-place cur[e]      (12.8 MB)
//   W_OFF    : w[e] = sigmoid(lg)/(imp+eps)       (12.8 MB)
//   PART_OFF : partials[NCHUNK][N_NODES]          (12.8 MB)
//   V_OFF    : packed v[N_NODES]                  (0.4 MB)
#define SD_OFF    64
#define VD_OFF    (SD_OFF + 2 * N_EDGES)
#define W_OFF     (VD_OFF + N_EDGES)
#define PART_OFF  (W_OFF + N_EDGES)
#define V_OFF     (PART_OFF + NCHUNK * N_NODES)
#define WS_FLOATS (V_OFF + N_NODES)

__device__ __forceinline__ float wave_reduce(float v) {
    #pragma unroll
    for (int off = 32; off > 0; off >>= 1) v += __shfl_down(v, off, 64);
    return v;
}

__device__ __forceinline__ void fadd_agent(float* p, float v) {
    unsafeAtomicAdd(p, v);
}

// ---------------- pass 0: pack v = nf[:,0] into a dense 400 KB table ----------------
__global__ __launch_bounds__(256) void packv_kernel(
    const float* __restrict__ nf, float* __restrict__ ws)
{
    const int i = blockIdx.x * blockDim.x + threadIdx.x;
    if (i < N_NODES) ws[V_OFF + i] = nf[i * 4];
}

// ---------------- pass 1: dtype-normalize edge_index -> int2 sd[] ----------------
// Pure vectorized transform: 2 edges per thread, int4 in / int4 out.
__global__ __launch_bounds__(256) void repack_kernel(
    const void* __restrict__ eidx, float* __restrict__ ws)
{
    const int* i32 = (const int*)eidx;

    // int64 values < 2^31 have zero hi-words at every odd int32 slot;
    // int32 has random node ids there (16 zeros ~ impossible).
    int any = 0;
    #pragma unroll
    for (int k = 1; k < 32; k += 2) any |= i32[k];
    const bool is32 = (any != 0);

    const int t = blockIdx.x * blockDim.x + threadIdx.x;   // pair index
    if (t >= N_EDGES / 2) return;

    int4 out;
    if (is32) {
        const int2 a = ((const int2*)i32)[t];                    // src pair
        const int2 b = ((const int2*)(i32 + N_EDGES))[t];        // dst pair
        out = make_int4(a.x, b.x, a.y, b.y);
    } else {
        const int4 a = ((const int4*)i32)[t];                    // src pair (2x i64)
        const int4 b = ((const int4*)(i32 + 2 * N_EDGES))[t];    // dst pair
        out = make_int4(a.x, b.x, a.z, b.z);
    }
    ((int4*)(ws + SD_OFF))[t] = out;
}

// ---------------- pass 2: variance sums + edge weight w[e] ----------------
__global__ __launch_bounds__(256) void varsum_kernel(
    const float2* __restrict__ params,
    const float*  __restrict__ logits,
    float*        __restrict__ ws)
{
    __shared__ float red[4][4];
    const float4* p4 = (const float4*)params;   // 2 edges per float4
    const float2* l2 = (const float2*)logits;
    float2*       w2 = (float2*)(ws + W_OFF);
    const int n4 = N_EDGES / 2;

    float s0 = 0.f, s1 = 0.f, q0 = 0.f, q1 = 0.f;
    for (int t = blockIdx.x * blockDim.x + threadIdx.x; t < n4;
         t += gridDim.x * blockDim.x) {
        const float4 pp = p4[t];
        const float2 lg = l2[t];
        float2 w;
        w.x = (1.0f / (1.0f + __expf(-lg.x))) / (pp.x + pp.y + EPS_F);
        w.y = (1.0f / (1.0f + __expf(-lg.y))) / (pp.z + pp.w + EPS_F);
        w2[t] = w;
        s0 += pp.x + pp.z; s1 += pp.y + pp.w;
        q0 += pp.x * pp.x + pp.z * pp.z;
        q1 += pp.y * pp.y + pp.w * pp.w;
    }
    s0 = wave_reduce(s0); s1 = wave_reduce(s1);
    q0 = wave_reduce(q0); q1 = wave_reduce(q1);

    const int wid = threadIdx.x >> 6;
    if ((threadIdx.x & 63) == 0) {
        red[wid][0] = s0; red[wid][1] = s1; red[wid][2] = q0; red[wid][3] = q1;
    }
    __syncthreads();
    if (threadIdx.x == 0) {
        float a0 = 0.f, a1 = 0.f, a2 = 0.f, a3 = 0.f;
        #pragma unroll
        for (int w = 0; w < 4; ++w) {
            a0 += red[w][0]; a1 += red[w][1]; a2 += red[w][2]; a3 += red[w][3];
        }
        fadd_agent(ws + 1, a0); fadd_agent(ws + 2, a1);
        fadd_agent(ws + 3, a2); fadd_agent(ws + 4, a3);
    }
}

// Common block geometry for the 3 edge-scan kernels: 256 blocks, 1024 thr.
// c = blockIdx&31 -> blockIdx%8 == c%8: all 8 slice-blocks of a chunk land on
// ONE XCD, so the 8x sd re-scan within each kernel is served by that XCD's L2.

// ---------------- pass 3: src-slice gather: vd[e] = v[src] ----------------
// Each edge's src lies in exactly one slice -> vd[e] written exactly once.
__global__ __launch_bounds__(1024) void vgatherS_kernel(float* __restrict__ ws)
{
    __shared__ float vs_lds[SLICE_N];   // 50 KB

    const int c  = blockIdx.x & (NCHUNK - 1);
    const int s  = blockIdx.x >> 5;
    const int lo = s * SLICE_N;

    const float* vtab = ws + V_OFF;
    for (int j = threadIdx.x; j < SLICE_N; j += 1024) vs_lds[j] = vtab[lo + j];
    __syncthreads();

    const int4* sdp = (const int4*)(ws + SD_OFF);
    float*      vd  = ws + VD_OFF;

    const int p0 = c * C_PAIRS;
    const int p1 = p0 + C_PAIRS;

    for (int p = p0 + threadIdx.x; p < p1; p += 1024) {
        const int4 q = sdp[p];                 // (s0,d0,s1,d1)
        const unsigned a = (unsigned)(q.x - lo);
        const unsigned b = (unsigned)(q.z - lo);
        if (a < SLICE_N) vd[2 * p]     = vs_lds[a];
        if (b < SLICE_N) vd[2 * p + 1] = vs_lds[b];
    }
}

// ---------------- pass 4: dst-slice: vd[e] <- |v_src - v_dst| * w[e] ----------------
// Each edge's dst lies in exactly one slice -> in-place rewrite is race-free.
__global__ __launch_bounds__(1024) void vgatherD_kernel(float* __restrict__ ws)
{
    __shared__ float vs_lds[SLICE_N];   // 50 KB

    const int c  = blockIdx.x & (NCHUNK - 1);
    const int s  = blockIdx.x >> 5;
    const int lo = s * SLICE_N;

    const float* vtab = ws + V_OFF;
    for (int j = threadIdx.x; j < SLICE_N; j += 1024) vs_lds[j] = vtab[lo + j];
    __syncthreads();

    const int4*   sdp = (const int4*)(ws + SD_OFF);
    float2*       vdp = (float2*)(ws + VD_OFF);
    const float2* wp  = (const float2*)(ws + W_OFF);

    const int p0 = c * C_PAIRS;
    const int p1 = p0 + C_PAIRS;

    for (int p = p0 + threadIdx.x; p < p1; p += 1024) {
        const int4 q = sdp[p];
        const unsigned a = (unsigned)(q.y - lo);   // dst of edge 2p
        const unsigned b = (unsigned)(q.w - lo);   // dst of edge 2p+1
        if ((a < SLICE_N) | (b < SLICE_N)) {
            const float2 vs = vdp[p];              // coalesced, unconditional
            const float2 w  = wp[p];
            float2 outv = vs;
            if (a < SLICE_N) outv.x = fabsf(vs.x - vs_lds[a]) * w.x;
            if (b < SLICE_N) outv.y = fabsf(vs.y - vs_lds[b]) * w.y;
            if (a < SLICE_N && b < SLICE_N) vdp[p] = outv;   // full 8B store
            else if (a < SLICE_N) ((float*)vdp)[2 * p]     = outv.x;
            else                  ((float*)vdp)[2 * p + 1]  = outv.y;
        }
    }
}

// ---------------- pass 5: LDS-binned scatter of precomputed cur ----------------
__global__ __launch_bounds__(1024) void scatter_kernel(float* __restrict__ ws)
{
    __shared__ float bins[SLICE_N];   // 50 KB

    const int c  = blockIdx.x & (NCHUNK - 1);
    const int s  = blockIdx.x >> 5;
    const int lo = s * SLICE_N;

    for (int j = threadIdx.x; j < SLICE_N; j += 1024) bins[j] = 0.f;
    __syncthreads();

    const int4*   sdp = (const int4*)(ws + SD_OFF);
    const float2* cur = (const float2*)(ws + VD_OFF);

    const int p0 = c * C_PAIRS;
    const int p1 = p0 + C_PAIRS;

    for (int p = p0 + threadIdx.x; p < p1; p += 1024) {
        const int4   q = sdp[p];
        const float2 u = cur[p];                   // coalesced, unconditional
        const unsigned s0 = (unsigned)(q.x - lo);
        const unsigned d0 = (unsigned)(q.y - lo);
        const unsigned s1 = (unsigned)(q.z - lo);
        const unsigned d1 = (unsigned)(q.w - lo);
        if (d0 < SLICE_N) atomicAdd(&bins[d0],  u.x);
        if (s0 < SLICE_N) atomicAdd(&bins[s0], -u.x);
        if (d1 < SLICE_N) atomicAdd(&bins[d1],  u.y);
        if (s1 < SLICE_N) atomicAdd(&bins[s1], -u.y);
    }
    __syncthreads();

    float* pt = ws + PART_OFF + (size_t)c * N_NODES + lo;
    for (int j = threadIdx.x; j < SLICE_N; j += 1024) pt[j] = bins[j];
}

// ---------------- pass 6: merge partials, sum of squares ----------------
__global__ __launch_bounds__(256) void kcl_kernel(float* __restrict__ ws)
{
    const int i = blockIdx.x * blockDim.x + threadIdx.x;
    float acc = 0.f;
    if (i < N_NODES) {
        const float* p = ws + PART_OFF + i;
        float s = 0.f;
        #pragma unroll 8
        for (int c = 0; c < NCHUNK; ++c) s += p[(size_t)c * N_NODES];
        acc = s * s;
    }
    acc = wave_reduce(acc);
    if ((threadIdx.x & 63) == 0) fadd_agent(ws + 5, acc);
}

__global__ void final_kernel(const float* __restrict__ ws, float* __restrict__ out)
{
    const float s0 = ws[1], s1 = ws[2], q0 = ws[3], q1 = ws[4], k = ws[5];
    const float n  = (float)N_EDGES;
    const float var0 = (q0 - s0 * s0 / n) / (n - 1.0f);
    const float var1 = (q1 - s1 * s1 / n) / (n - 1.0f);
    out[0] = k / (float)N_NODES + 0.5f * (var0 + var1);
}

// ---------------- fallback (ws too small): agent-atomic scatter ----------------
#define FB_NODE_OFF 64
__global__ __launch_bounds__(256) void edge_kernel_fb(
    const float*  __restrict__ nf,
    const void*   __restrict__ eidx,
    const float*  __restrict__ logits,
    const float2* __restrict__ params,
    float*        __restrict__ ws)
{
    const int*       i32 = (const int*)eidx;
    const long long* i64 = (const long long*)eidx;
    int any = 0;
    #pragma unroll
    for (int k = 1; k < 32; k += 2) any |= i32[k];
    const bool is32 = (any != 0);

    float* node_sum = ws + FB_NODE_OFF;
    float* acc      = ws + 1;

    float s0 = 0.f, s1 = 0.f, q0 = 0.f, q1 = 0.f;
    const int tid    = blockIdx.x * blockDim.x + threadIdx.x;
    const int stride = gridDim.x * blockDim.x;
    for (int i = tid; i < N_EDGES; i += stride) {
        int src, dst;
        if (is32) { src = i32[i]; dst = i32[N_EDGES + i]; }
        else      { src = (int)i64[i]; dst = (int)i64[N_EDGES + i]; }
        const float2 ep = params[i];
        const float  p  = 1.0f / (1.0f + __expf(-logits[i]));
        const float cur = fabsf(nf[src * 4] - nf[dst * 4]) / (ep.x + ep.y + EPS_F) * p;
        fadd_agent(node_sum + dst,  cur);
        fadd_agent(node_sum + src, -cur);
        s0 += ep.x; s1 += ep.y; q0 += ep.x * ep.x; q1 += ep.y * ep.y;
    }
    s0 = wave_reduce(s0); s1 = wave_reduce(s1);
    q0 = wave_reduce(q0); q1 = wave_reduce(q1);
    if ((threadIdx.x & 63) == 0) {
        fadd_agent(acc + 0, s0); fadd_agent(acc + 1, s1);
        fadd_agent(acc + 2, q0); fadd_agent(acc + 3, q1);
    }
}

__global__ __launch_bounds__(256) void kcl_kernel_fb(float* __restrict__ ws)
{
    const float* node_sum = ws + FB_NODE_OFF;
    float acc = 0.f;
    const int tid    = blockIdx.x * blockDim.x + threadIdx.x;
    const int stride = gridDim.x * blockDim.x;
    for (int i = tid; i < N_NODES; i += stride) {
        const float v = node_sum[i];
        acc += v * v;
    }
    acc = wave_reduce(acc);
    if ((threadIdx.x & 63) == 0) fadd_agent(ws + 5, acc);
}

extern "C" void kernel_launch(void* const* d_in, const int* in_sizes, int n_in,
                              void* d_out, int out_size, void* d_ws, size_t ws_size,
                              hipStream_t stream) {
    const float*  nf     = (const float*)d_in[0];
    const void*   eidx   = d_in[1];
    const float*  logits = (const float*)d_in[2];
    const float2* params = (const float2*)d_in[3];
    float* ws  = (float*)d_ws;
    float* out = (float*)d_out;

    const size_t need = (size_t)WS_FLOATS * sizeof(float);   // 61.4 MiB (same as R7-R9)

    if (ws_size >= need) {
        hipMemsetAsync(d_ws, 0, 256, stream);
        packv_kernel<<<(N_NODES + 255) / 256, 256, 0, stream>>>(nf, ws);
        repack_kernel<<<(N_EDGES / 2 + 255) / 256, 256, 0, stream>>>(eidx, ws);
        varsum_kernel<<<1024, 256, 0, stream>>>(params, logits, ws);
        vgatherS_kernel<<<NCHUNK * NSLICE, 1024, 0, stream>>>(ws);
        vgatherD_kernel<<<NCHUNK * NSLICE, 1024, 0, stream>>>(ws);
        scatter_kernel<<<NCHUNK * NSLICE, 1024, 0, stream>>>(ws);
        kcl_kernel<<<(N_NODES + 255) / 256, 256, 0, stream>>>(ws);
    } else {
        hipMemsetAsync(d_ws, 0, 256 + (size_t)N_NODES * sizeof(float), stream);
        edge_kernel_fb<<<2048, 256, 0, stream>>>(nf, eidx, logits, params, ws);
        kcl_kernel_fb<<<200, 256, 0, stream>>>(ws);
    }

    final_kernel<<<1, 1, 0, stream>>>(ws, out);
}